// Round 17
// baseline (208.079 us; speedup 1.0000x reference)
//
#include <hip/hip_runtime.h>
#include <math.h>

// Problem constants (from reference setup_inputs)
#define HDIM 1024
#define NHEAD 16
#define HD 64
#define LM 64          // NUM_LANDMARKS
#define MS 512         // memory slots
#define KSEL 32        // top_k
#define NB 2
#define NS 4096
#define NTOK (NB*NS)   // 8192

typedef __attribute__((ext_vector_type(8))) short short8;
typedef __attribute__((ext_vector_type(4))) float f32x4;
typedef __attribute__((ext_vector_type(4))) unsigned short us4;

__device__ __forceinline__ unsigned short f2bf(float f) {
  unsigned int u = __float_as_uint(f);
  unsigned int r = (u + 0x7fffu + ((u >> 16) & 1u)) >> 16;
  return (unsigned short)r;
}
__device__ __forceinline__ float bf2f(unsigned short u) {
  return __uint_as_float(((unsigned int)u) << 16);
}

__device__ __forceinline__ void gload_lds16(const unsigned short* g, unsigned short* l) {
  __builtin_amdgcn_global_load_lds(
      (const __attribute__((address_space(1))) unsigned int*)g,
      (__attribute__((address_space(3))) unsigned int*)l,
      16, 0, 0);
}

// BK=64 tile stager (used by gemm_fused_out): XOR-swizzled source chunks.
#define STAGE64(gbase, k0, LDA, lds)                                          \
  {                                                                           \
    const unsigned short* _s = (gbase) + (k0) + gchk*8;                       \
    gload_lds16(_s,                 (lds) + tid*8);                           \
    gload_lds16(_s + (size_t)32*(LDA), (lds) + 2048 + tid*8);                 \
    gload_lds16(_s + (size_t)64*(LDA), (lds) + 4096 + tid*8);                 \
    gload_lds16(_s + (size_t)96*(LDA), (lds) + 6144 + tid*8);                 \
  }

// ---------------------------------------------------------------------------
// K1 (fused): blocks [0,2048): wave-per-row importance + gate + hs->bf16.
//             blocks [2048,7168): weight transpose/convert prep (flat decode).
// ---------------------------------------------------------------------------
__global__ __launch_bounds__(256) void imp_prep_kernel(
    const float* __restrict__ hs, const float* __restrict__ gw,
    const float* __restrict__ gb, float* __restrict__ imp,
    float* __restrict__ gate, unsigned short* __restrict__ hsb,
    const float* __restrict__ Wk, const float* __restrict__ Wv,
    const float* __restrict__ Wq, const float* __restrict__ Wo,
    const float* __restrict__ mk, const float* __restrict__ mv,
    unsigned short* __restrict__ Wkvt, unsigned short* __restrict__ Wcat,
    unsigned short* __restrict__ Wot, unsigned short* __restrict__ mvT) {
  __shared__ float tile[32][33];
  if (blockIdx.x < 2048) {
    // ---- importance + gate + bf16 conversion ----
    const int lane = threadIdx.x & 63, wave = threadIdx.x >> 6;
    const int row = blockIdx.x*4 + wave;
    float ss = 0.f, dg = 0.f;
#pragma unroll
    for (int c = 0; c < 4; ++c) {
      const int d = c*256 + lane*4;
      const float4 hv = *(const float4*)(hs + (size_t)row*HDIM + d);
      const float4 gv = *(const float4*)(gw + d);
      ss += hv.x*hv.x + hv.y*hv.y + hv.z*hv.z + hv.w*hv.w;
      dg += hv.x*gv.x + hv.y*gv.y + hv.z*gv.z + hv.w*gv.w;
      us4 hb;
      hb.x = f2bf(hv.x); hb.y = f2bf(hv.y); hb.z = f2bf(hv.z); hb.w = f2bf(hv.w);
      *(us4*)(hsb + (size_t)row*HDIM + d) = hb;
    }
#pragma unroll
    for (int off = 32; off > 0; off >>= 1) {
      ss += __shfl_xor(ss, off);
      dg += __shfl_xor(dg, off);
    }
    if (lane == 0) {
      imp[row] = ss;
      gate[row] = 1.f/(1.f + expf(-(dg + gb[0])));
    }
    return;
  }
  // ---- prep ----
  const int flat = blockIdx.x - 2048;       // 0..5119
  const int z = flat >> 10;                 // 0..4
  const int rem = flat & 1023;
  const int byy = rem >> 5, bxx = rem & 31;
  const int tx = threadIdx.x & 31, ty = threadIdx.x >> 5;
  if (z < 4) {
    const float* W = (z == 0) ? Wk : (z == 1) ? Wv : (z == 2) ? Wq : Wo;
    unsigned short* Wt = (z == 0) ? Wkvt
                       : (z == 1) ? (Wkvt + (size_t)HDIM*HDIM)
                       : (z == 2) ? Wcat : Wot;
    const int bx = bxx * 32, by = byy * 32;
#pragma unroll
    for (int i = 0; i < 32; i += 8)
      tile[ty + i][tx] = W[(size_t)(by + ty + i)*HDIM + bx + tx];
    __syncthreads();
#pragma unroll
    for (int i = 0; i < 32; i += 8)
      Wt[(size_t)(bx + ty + i)*HDIM + by + tx] = f2bf(tile[tx][ty + i]);
  } else {
    const int blk = byy*32 + bxx;           // 0..1023
    if (blk < 512) {
      const int off = (blk << 10) + threadIdx.x*4;
      const float4 v = *(const float4*)&mk[off];
      us4 w;
      w.x = f2bf(v.x); w.y = f2bf(v.y); w.z = f2bf(v.z); w.w = f2bf(v.w);
      *(us4*)&(Wcat + (size_t)HDIM*HDIM)[off] = w;
    } else {
      const int t = blk - 512;
      const int by = (t >> 5) * 32;
      const int bx = (t & 31) * 32;
#pragma unroll
      for (int i = 0; i < 32; i += 8)
        tile[ty + i][tx] = mv[(size_t)(by + ty + i)*HDIM + bx + tx];
      __syncthreads();
#pragma unroll
      for (int i = 0; i < 32; i += 8)
        mvT[(size_t)(bx + ty + i)*MS + by + tx] = f2bf(tile[tx][ty + i]);
    }
  }
}

// ---------------------------------------------------------------------------
// K2: landmark selection by exact rank, single kernel. Block stages the full
// importance vector (16 KB) in LDS; each thread counts its candidate's rank
// (jax tie-break: value desc, idx asc) over all 4096; rank<64 -> scatter.
// grid (NS/256, NB) = 32 blocks; broadcast LDS reads (conflict-free).
// ---------------------------------------------------------------------------
__global__ __launch_bounds__(256) void lm_rank_kernel(
    const float* __restrict__ imp, int* __restrict__ lm_idx) {
  const int b = blockIdx.y;
  const int i = blockIdx.x*256 + threadIdx.x;
  __shared__ float v[NS];   // 16 KiB
  for (int j = threadIdx.x*4; j < NS; j += 1024)
    *(float4*)&v[j] = *(const float4*)&imp[b*NS + j];
  __syncthreads();
  const float mine = v[i];
  int c = 0;
#pragma unroll 4
  for (int p = 0; p < NS; p += 4) {
    const float4 t = *(const float4*)&v[p];
    c += (t.x > mine) || (t.x == mine && (p+0) < i);
    c += (t.y > mine) || (t.y == mine && (p+1) < i);
    c += (t.z > mine) || (t.z == mine && (p+2) < i);
    c += (t.w > mine) || (t.w == mine && (p+3) < i);
  }
  if (c < LM) lm_idx[b*LM + c] = i;
}

// ---------------------------------------------------------------------------
// K3: K/V projection as bf16 MFMA GEMM, split-K=4, landmark gather INLINED.
// ---------------------------------------------------------------------------
__global__ __launch_bounds__(256) void kvproj_gemm_kernel(
    const unsigned short* __restrict__ hsb, const int* __restrict__ lmi,
    const unsigned short* __restrict__ Wkvt, float* __restrict__ part) {
  __shared__ __align__(16) unsigned short As[128*32];
  __shared__ __align__(16) unsigned short Bs[128*32];
  const int tid = threadIdx.x;
  const int lane = tid & 63, wave = tid >> 6;
  const int wr = wave >> 1, wc = wave & 1;
  const int col0 = blockIdx.x << 7;
  const int sp = blockIdx.y;
  const int k00 = sp << 8;

  f32x4 acc[4][4];
#pragma unroll
  for (int m = 0; m < 4; ++m)
#pragma unroll
    for (int n = 0; n < 4; ++n) acc[m][n] = (f32x4)(0.f);

  const int srow = tid >> 2;
  const int sk   = (tid & 3) << 3;
  const int i0 = lmi[srow];            // b=0 landmark row
  const int i1 = lmi[64 + srow];       // b=1 landmark row
  const unsigned short* gA0 = hsb + (size_t)i0*HDIM + sk;
  const unsigned short* gA1 = hsb + ((size_t)NS + i1)*HDIM + sk;
  const unsigned short* gB  = Wkvt + (size_t)(col0 + srow)*HDIM + sk;
  const int fr = lane & 15;
  const int fk = (lane >> 4) << 3;
  const int fg = lane >> 4;

  for (int k0 = k00; k0 < k00 + 256; k0 += 32) {
    gload_lds16(gA0 + k0,            As + tid*8);
    gload_lds16(gA1 + k0,            As + 2048 + tid*8);
    gload_lds16(gB + k0,             Bs + tid*8);
    gload_lds16(gB + 64*HDIM + k0,   Bs + 2048 + tid*8);
    __syncthreads();
    short8 af[4], bf[4];
#pragma unroll
    for (int m = 0; m < 4; ++m)
      af[m] = *(const short8*)&As[(wr*64 + m*16 + fr)*32 + fk];
#pragma unroll
    for (int n = 0; n < 4; ++n)
      bf[n] = *(const short8*)&Bs[(wc*64 + n*16 + fr)*32 + fk];
#pragma unroll
    for (int m = 0; m < 4; ++m)
#pragma unroll
      for (int n = 0; n < 4; ++n)
        acc[m][n] = __builtin_amdgcn_mfma_f32_16x16x32_bf16(af[m], bf[n], acc[m][n], 0, 0, 0);
    __syncthreads();
  }
#pragma unroll
  for (int m = 0; m < 4; ++m)
#pragma unroll
    for (int n = 0; n < 4; ++n) {
      const int colg = col0 + wc*64 + n*16 + fr;
#pragma unroll
      for (int r = 0; r < 4; ++r) {
        const int row = wr*64 + m*16 + fg*4 + r;
        part[((size_t)(sp*128 + row))*2048 + colg] = acc[m][n][r];
      }
    }
}

// K3c: reduce 4 K-split partials + bias -> bf16 K (row-major) and V^T.
__global__ __launch_bounds__(256) void kv_reduce2_kernel(
    const float* __restrict__ part, const float* __restrict__ bk,
    const float* __restrict__ bv, unsigned short* __restrict__ kbb,
    unsigned short* __restrict__ vbbT) {
  const int row = blockIdx.y;                     // 0..127 = b*64 + l
  const int col = blockIdx.x*256 + threadIdx.x;   // 0..2047
  float s = 0.f;
#pragma unroll
  for (int sp = 0; sp < 4; ++sp)
    s += part[((size_t)(sp*128 + row))*2048 + col];
  if (col < HDIM) {
    kbb[(size_t)row*HDIM + col] = f2bf(s + bk[col]);
  } else {
    const int d = col - HDIM;
    const int b = row >> 6, l = row & 63;
    vbbT[(size_t)b*65536 + (size_t)d*64 + l] = f2bf(s + bv[d]);
  }
}

// ---------------------------------------------------------------------------
// K4: FUSED GEMM + ATTENTION.  [q | msc] = hsb @ Wcat^T (BK=32, 128x128).
// bx<8: q-tile (2 heads) in registers; per-wave landmark attention (two
//       32-row passes) via 4KB per-wave LDS buffer (linear layout — swizzle
//       variant spilled VGPRs, R14). bx>=8: msc epilogue.
// ---------------------------------------------------------------------------
__global__ __launch_bounds__(256, 3) void gemm_qattn_kernel(
    const unsigned short* __restrict__ A,    // hsb
    const unsigned short* __restrict__ Bt,   // Wcat [1536][1024]
    const float* __restrict__ bq,
    const unsigned short* __restrict__ kbb,  // [NB*64][1024]
    const unsigned short* __restrict__ vbbT, // [NB][1024][64]
    unsigned short* __restrict__ ctxb, float* __restrict__ msc) {
  __shared__ __align__(16) unsigned short As[128*32];   // 8 KiB (later wavebuf 0,1)
  __shared__ __align__(16) unsigned short Bs[128*32];   // 8 KiB (later wavebuf 2,3)
  __shared__ __align__(16) unsigned short Ks[2*64*64];  // 16 KiB [h][lm][d]
  __shared__ __align__(16) unsigned short Vt[2*64*64];  // 16 KiB [h][d][lm]
  const int tid = threadIdx.x;
  const int lane = tid & 63, wave = tid >> 6;
  const int wr = wave >> 1, wc = wave & 1;
  const int wg = blockIdx.x;                    // 0..767
  const int swz = (wg & 7)*96 + (wg >> 3);      // bijective XCD swizzle
  const int bx = swz % 12, by = swz / 12;
  const int row0 = by << 7, col0 = bx << 7;
  const int fr = lane & 15;
  const int fk = (lane >> 4) << 3;
  const int fg = lane >> 4;

  // issue K/V staging early (q-blocks only); k-loop barriers drain it
  if (bx < 8) {
    const int b = by >> 5;
#pragma unroll
    for (int it = 0; it < 4; ++it) {
      const int c = it*256 + tid;               // 0..1023
      const int hh = c >> 9, l = (c >> 3) & 63, ch = c & 7;
      gload_lds16(kbb + (size_t)(b*64 + l)*HDIM + (bx*2 + hh)*64 + ch*8,
                  Ks + c*8);
    }
#pragma unroll
    for (int it = 0; it < 4; ++it) {
      const int c = it*256 + tid;
      const int hh = c >> 9, dr = (c >> 3) & 63, ch = c & 7;
      gload_lds16(vbbT + (size_t)(by >> 5)*65536 + (size_t)((bx*2 + hh)*64 + dr)*64 + ch*8,
                  Vt + c*8);
    }
  }

  f32x4 acc[4][4];
#pragma unroll
  for (int m = 0; m < 4; ++m)
#pragma unroll
    for (int n = 0; n < 4; ++n) acc[m][n] = (f32x4)(0.f);

  const int srow = tid >> 2;
  const int sk   = (tid & 3) << 3;
  const unsigned short* gA = A  + (size_t)(row0 + srow)*HDIM + sk;
  const unsigned short* gB = Bt + (size_t)(col0 + srow)*HDIM + sk;

  for (int k0 = 0; k0 < HDIM; k0 += 32) {
    gload_lds16(gA + k0,             As + tid*8);
    gload_lds16(gA + 64*HDIM + k0,   As + 2048 + tid*8);
    gload_lds16(gB + k0,             Bs + tid*8);
    gload_lds16(gB + 64*HDIM + k0,   Bs + 2048 + tid*8);
    __syncthreads();
    short8 af[4], bf[4];
#pragma unroll
    for (int m = 0; m < 4; ++m)
      af[m] = *(const short8*)&As[(wr*64 + m*16 + fr)*32 + fk];
#pragma unroll
    for (int n = 0; n < 4; ++n)
      bf[n] = *(const short8*)&Bs[(wc*64 + n*16 + fr)*32 + fk];
#pragma unroll
    for (int m = 0; m < 4; ++m)
#pragma unroll
      for (int n = 0; n < 4; ++n)
        acc[m][n] = __builtin_amdgcn_mfma_f32_16x16x32_bf16(af[m], bf[n], acc[m][n], 0, 0, 0);
    __syncthreads();
  }

  if (bx >= 8) {
    // msc epilogue
#pragma unroll
    for (int m = 0; m < 4; ++m)
#pragma unroll
      for (int n = 0; n < 4; ++n) {
        const int c2 = col0 + wc*64 + n*16 + fr - HDIM;
#pragma unroll
        for (int r = 0; r < 4; ++r) {
          const int row = row0 + wr*64 + m*16 + fg*4 + r;
          msc[(size_t)row*MS + c2] = acc[m][n][r]*0.03125f;
        }
      }
    return;
  }

  // ---- per-wave landmark attention (64 tokens x 1 head, 2 passes of 32) ----
  float bqv[4];
#pragma unroll
  for (int n = 0; n < 4; ++n) bqv[n] = bq[col0 + wc*64 + n*16 + fr];

  unsigned short* wb = (wave < 2) ? (As + wave*2048) : (Bs + (wave - 2)*2048);
  const int hb = wc*4096;   // head base into Ks/Vt

#pragma unroll
  for (int pass = 0; pass < 2; ++pass) {
    // q (+bias) -> bf16 -> wavebuf [32][64]
#pragma unroll
    for (int m2 = 0; m2 < 2; ++m2)
#pragma unroll
      for (int n = 0; n < 4; ++n)
#pragma unroll
        for (int r = 0; r < 4; ++r)
          wb[(m2*16 + fg*4 + r)*64 + n*16 + fr] =
              f2bf(acc[pass*2 + m2][n][r] + bqv[n]);
    __builtin_amdgcn_wave_barrier();

    // QK^T: scores [32 tok][64 lm]
    f32x4 sc_[2][4];
#pragma unroll
    for (int m2 = 0; m2 < 2; ++m2)
#pragma unroll
      for (int n = 0; n < 4; ++n) sc_[m2][n] = (f32x4)(0.f);
#pragma unroll
    for (int ks = 0; ks < 2; ++ks) {
      short8 af[2], bf[4];
#pragma unroll
      for (int m2 = 0; m2 < 2; ++m2)
        af[m2] = *(const short8*)&wb[(m2*16 + fr)*64 + ks*32 + fk];
#pragma unroll
      for (int n = 0; n < 4; ++n)
        bf[n] = *(const short8*)&Ks[hb + (n*16 + fr)*64 + ks*32 + fk];
#pragma unroll
      for (int m2 = 0; m2 < 2; ++m2)
#pragma unroll
        for (int n = 0; n < 4; ++n)
          sc_[m2][n] = __builtin_amdgcn_mfma_f32_16x16x32_bf16(af[m2], bf[n], sc_[m2][n], 0, 0, 0);
    }

    // in-register row softmax; P -> wavebuf
#pragma unroll
    for (int m2 = 0; m2 < 2; ++m2) {
#pragma unroll
      for (int r = 0; r < 4; ++r) {
        float p0 = sc_[m2][0][r]*0.125f, p1 = sc_[m2][1][r]*0.125f;
        float p2 = sc_[m2][2][r]*0.125f, p3 = sc_[m2][3][r]*0.125f;
        float mx = fmaxf(fmaxf(p0, p1), fmaxf(p2, p3));
#pragma unroll
        for (int off = 1; off < 16; off <<= 1) mx = fmaxf(mx, __shfl_xor(mx, off));
        p0 = expf(p0 - mx); p1 = expf(p1 - mx); p2 = expf(p2 - mx); p3 = expf(p3 - mx);
        float sm = p0 + p1 + p2 + p3;
#pragma unroll
        for (int off = 1; off < 16; off <<= 1) sm += __shfl_xor(sm, off);
        const float inv = 1.f/sm;
        const int prow = (m2*16 + fg*4 + r)*64;
        wb[prow + 0*16 + fr] = f2bf(p0*inv);
        wb[prow + 1*16 + fr] = f2bf(p1*inv);
        wb[prow + 2*16 + fr] = f2bf(p2*inv);
        wb[prow + 3*16 + fr] = f2bf(p3*inv);
      }
    }
    __builtin_amdgcn_wave_barrier();

    // PV: ctx [32 tok][64 dims]
    f32x4 oc_[2][4];
#pragma unroll
    for (int m2 = 0; m2 < 2; ++m2)
#pragma unroll
      for (int n = 0; n < 4; ++n) oc_[m2][n] = (f32x4)(0.f);
#pragma unroll
    for (int ks = 0; ks < 2; ++ks) {
      short8 af[2], bf[4];
#pragma unroll
      for (int m2 = 0; m2 < 2; ++m2)
        af[m2] = *(const short8*)&wb[(m2*16 + fr)*64 + ks*32 + fk];
#pragma unroll
      for (int n = 0; n < 4; ++n)
        bf[n] = *(const short8*)&Vt[hb + (n*16 + fr)*64 + ks*32 + fk];
#pragma unroll
      for (int m2 = 0; m2 < 2; ++m2)
#pragma unroll
        for (int n = 0; n < 4; ++n)
          oc_[m2][n] = __builtin_amdgcn_mfma_f32_16x16x32_bf16(af[m2], bf[n], oc_[m2][n], 0, 0, 0);
    }
#pragma unroll
    for (int m2 = 0; m2 < 2; ++m2)
#pragma unroll
      for (int n = 0; n < 4; ++n)
#pragma unroll
        for (int r = 0; r < 4; ++r) {
          const int tok = row0 + wr*64 + pass*32 + m2*16 + fg*4 + r;
          ctxb[(size_t)tok*HDIM + col0 + wc*64 + n*16 + fr] = f2bf(oc_[m2][n][r]);
        }
    __builtin_amdgcn_wave_barrier();
  }
}

// ---------------------------------------------------------------------------
// K8a: wave-per-token top-32 THRESHOLD selection -> gate-scaled dense weight
// row Wm[token][m] (bf16). Lane-contiguous coalesced I/O.
// ---------------------------------------------------------------------------
__global__ __launch_bounds__(256) void sel_kernel(
    const float* __restrict__ msc, const float* __restrict__ gate,
    unsigned short* __restrict__ Wm) {
  const int tid = threadIdx.x;
  const int lane = tid & 63, wave = tid >> 6;
  const int token = blockIdx.x*4 + wave;

  __shared__ __align__(16) int s_hist[4][256];
  __shared__ unsigned long long s_list[4][256];
  __shared__ int s_B[4], s_above[4], s_nlist[4];

  *(int4*)&s_hist[wave][lane*4] = make_int4(0, 0, 0, 0);
  if (lane == 0) s_nlist[wave] = 0;

  float v[8];
  {
    const float4 va = *(const float4*)&msc[(size_t)token*MS + lane*8];
    const float4 vb = *(const float4*)&msc[(size_t)token*MS + lane*8 + 4];
    v[0] = va.x; v[1] = va.y; v[2] = va.z; v[3] = va.w;
    v[4] = vb.x; v[5] = vb.y; v[6] = vb.z; v[7] = vb.w;
  }

  float mx = v[0], mn = v[0];
#pragma unroll
  for (int j = 1; j < 8; ++j) { mx = fmaxf(mx, v[j]); mn = fminf(mn, v[j]); }
#pragma unroll
  for (int off = 32; off > 0; off >>= 1) {
    mx = fmaxf(mx, __shfl_xor(mx, off));
    mn = fminf(mn, __shfl_xor(mn, off));
  }
  const float range = mx - mn;
  const float scale = (range > 1e-20f) ? 255.f/range : 0.f;

  __builtin_amdgcn_wave_barrier();
  int bins[8];
#pragma unroll
  for (int j = 0; j < 8; ++j) {
    int b = (int)((v[j] - mn)*scale);
    bins[j] = b > 255 ? 255 : b;
    atomicAdd(&s_hist[wave][bins[j]], 1);
  }
  __builtin_amdgcn_wave_barrier();

  const int4 c = *(const int4*)&s_hist[wave][lane*4];
  const int lane_total = c.x + c.y + c.z + c.w;
  int sfx = lane_total;
#pragma unroll
  for (int off = 1; off < 64; off <<= 1) {
    const int src = lane + off;
    int y = __shfl(sfx, src < 64 ? src : lane);
    sfx += (src < 64) ? y : 0;
  }
  const int beyond = sfx - lane_total;
  const int s3 = c.w + beyond;
  const int s2 = c.z + s3;
  const int s1 = c.y + s2;
  const int s0 = c.x + s1;
  int Bl = -1, abv = 0;
  if (s0 >= KSEL && s1 < KSEL) { Bl = lane*4 + 0; abv = s1; }
  if (s1 >= KSEL && s2 < KSEL) { Bl = lane*4 + 1; abv = s2; }
  if (s2 >= KSEL && s3 < KSEL) { Bl = lane*4 + 2; abv = s3; }
  if (s3 >= KSEL && beyond < KSEL) { Bl = lane*4 + 3; abv = beyond; }
  if (Bl >= 0) { s_B[wave] = Bl; s_above[wave] = abv; }
  __builtin_amdgcn_wave_barrier();
  const int B = s_B[wave];
  const int rem = KSEL - s_above[wave];

#pragma unroll
  for (int j = 0; j < 8; ++j) {
    if (bins[j] == B) {
      const unsigned int u = __float_as_uint(v[j]);
      const unsigned int vk = (u & 0x80000000u) ? ~u : (u | 0x80000000u);
      const int p = atomicAdd(&s_nlist[wave], 1);
      if (p < 256)
        s_list[wave][p] = ((unsigned long long)vk << 32) | (unsigned int)~(lane*8 + j);
    }
  }
  __builtin_amdgcn_wave_barrier();

  const int nl = s_nlist[wave] < 256 ? s_nlist[wave] : 256;
  unsigned long long T = ~0ull;
  for (int r = 0; r < rem; ++r) {
    unsigned long long best = 0; int pos = -1;
    for (int i = lane; i < nl; i += 64)
      if (s_list[wave][i] > best) { best = s_list[wave][i]; pos = i; }
#pragma unroll
    for (int off = 32; off > 0; off >>= 1) {
      const unsigned long long ob = __shfl_xor(best, off);
      const int op = __shfl_xor(pos, off);
      if (ob > best) { best = ob; pos = op; }
    }
    if (lane == 0) s_list[wave][pos] = 0;
    T = best;
    __builtin_amdgcn_wave_barrier();
  }

  float e[8];
  float esum = 0.f;
#pragma unroll
  for (int j = 0; j < 8; ++j) {
    bool sel = bins[j] > B;
    if (!sel && bins[j] == B) {
      const unsigned int u = __float_as_uint(v[j]);
      const unsigned int vk = (u & 0x80000000u) ? ~u : (u | 0x80000000u);
      const unsigned long long key =
          ((unsigned long long)vk << 32) | (unsigned int)~(lane*8 + j);
      sel = key >= T;
    }
    e[j] = sel ? expf(v[j] - mx) : 0.f;
    esum += e[j];
  }
#pragma unroll
  for (int off = 32; off > 0; off >>= 1) esum += __shfl_xor(esum, off);
  const float ginv = gate[token]/esum;
  us4 w0, w1;
  w0.x = f2bf(e[0]*ginv); w0.y = f2bf(e[1]*ginv);
  w0.z = f2bf(e[2]*ginv); w0.w = f2bf(e[3]*ginv);
  w1.x = f2bf(e[4]*ginv); w1.y = f2bf(e[5]*ginv);
  w1.z = f2bf(e[6]*ginv); w1.w = f2bf(e[7]*ginv);
  *(us4*)&Wm[(size_t)token*MS + lane*8]     = w0;
  *(us4*)&Wm[(size_t)token*MS + lane*8 + 4] = w1;
}

// ---------------------------------------------------------------------------
// K9: FUSED output GEMM (BK=64, swizzled): out = ctx@Wot^T + bo + Wm'@mvT^T.
// ---------------------------------------------------------------------------
__global__ __launch_bounds__(256) void gemm_fused_out_kernel(
    const unsigned short* __restrict__ A,   // ctxb [NTOK][HDIM]
    const unsigned short* __restrict__ Bt,  // Wot  [HDIM][HDIM]
    const unsigned short* __restrict__ Wm,  // [NTOK][MS] gate-scaled bf16
    const unsigned short* __restrict__ mvT, // [HDIM][MS]
    const float* __restrict__ bias, float* __restrict__ out) {
  __shared__ __align__(16) unsigned short As[128*64];
  __shared__ __align__(16) unsigned short Bs[128*64];
  const int tid = threadIdx.x;
  const int lane = tid & 63, wave = tid >> 6;
  const int wr = wave >> 1, wc = wave & 1;
  const int wg = blockIdx.x;
  const int swz = (wg & 7)*64 + (wg >> 3);
  const int bx = swz & 7, by = swz >> 3;
  const int row0 = by << 7, col0 = bx << 7;

  f32x4 acc[4][4];
#pragma unroll
  for (int m = 0; m < 4; ++m)
#pragma unroll
    for (int n = 0; n < 4; ++n) acc[m][n] = (f32x4)(0.f);

  const int srow = tid >> 3;
  const int gchk = (tid & 7) ^ (srow & 7);
  const int fr = lane & 15;
  const int fg = lane >> 4;
  const int ca = ((0*4 + fg) ^ (fr & 7)) * 8;
  const int cb = ((1*4 + fg) ^ (fr & 7)) * 8;

  {
    const unsigned short* gA = A  + (size_t)(row0 + srow)*HDIM;
    const unsigned short* gB = Bt + (size_t)(col0 + srow)*HDIM;
    for (int k0 = 0; k0 < HDIM; k0 += 64) {
      STAGE64(gA, k0, HDIM, As);
      STAGE64(gB, k0, HDIM, Bs);
      __syncthreads();
#pragma unroll
      for (int kh = 0; kh < 2; ++kh) {
        const int cc = kh ? cb : ca;
        short8 af[4], bf[4];
#pragma unroll
        for (int m = 0; m < 4; ++m)
          af[m] = *(const short8*)&As[(wr*64 + m*16 + fr)*64 + cc];
#pragma unroll
        for (int n = 0; n < 4; ++n)
          bf[n] = *(const short8*)&Bs[(wc*64 + n*16 + fr)*64 + cc];
#pragma unroll
        for (int m = 0; m < 4; ++m)
#pragma unroll
          for (int n = 0; n < 4; ++n)
            acc[m][n] = __builtin_amdgcn_mfma_f32_16x16x32_bf16(af[m], bf[n], acc[m][n], 0, 0, 0);
      }
      __syncthreads();
    }
  }
  {
    const unsigned short* gA = Wm  + (size_t)(row0 + srow)*MS;
    const unsigned short* gB = mvT + (size_t)(col0 + srow)*MS;
    for (int k0 = 0; k0 < MS; k0 += 64) {
      STAGE64(gA, k0, MS, As);
      STAGE64(gB, k0, MS, Bs);
      __syncthreads();
#pragma unroll
      for (int kh = 0; kh < 2; ++kh) {
        const int cc = kh ? cb : ca;
        short8 af[4], bf[4];
#pragma unroll
        for (int m = 0; m < 4; ++m)
          af[m] = *(const short8*)&As[(wr*64 + m*16 + fr)*64 + cc];
#pragma unroll
        for (int n = 0; n < 4; ++n)
          bf[n] = *(const short8*)&Bs[(wc*64 + n*16 + fr)*64 + cc];
#pragma unroll
        for (int m = 0; m < 4; ++m)
#pragma unroll
          for (int n = 0; n < 4; ++n)
            acc[m][n] = __builtin_amdgcn_mfma_f32_16x16x32_bf16(af[m], bf[n], acc[m][n], 0, 0, 0);
      }
      __syncthreads();
    }
  }

#pragma unroll
  for (int m = 0; m < 4; ++m) {
#pragma unroll
    for (int n = 0; n < 4; ++n) {
      const int col = col0 + wc*64 + n*16 + fr;
      const float bb = bias[col];
#pragma unroll
      for (int r = 0; r < 4; ++r) {
        const int row = row0 + wr*64 + m*16 + fg*4 + r;
        out[(size_t)row*HDIM + col] = acc[m][n][r] + bb;
      }
    }
  }
}

// ---------------------------------------------------------------------------
extern "C" void kernel_launch(void* const* d_in, const int* in_sizes, int n_in,
                              void* d_out, int out_size, void* d_ws, size_t ws_size,
                              hipStream_t stream) {
  const float* hs = (const float*)d_in[0];
  const float* Wq = (const float*)d_in[1];
  const float* bq = (const float*)d_in[2];
  const float* Wk = (const float*)d_in[3];
  const float* bk = (const float*)d_in[4];
  const float* Wv = (const float*)d_in[5];
  const float* bv = (const float*)d_in[6];
  const float* Wo = (const float*)d_in[7];
  const float* bo = (const float*)d_in[8];
  const float* mk = (const float*)d_in[9];
  const float* mv = (const float*)d_in[10];
  const float* gw = (const float*)d_in[11];
  const float* gb = (const float*)d_in[12];
  float* out = (float*)d_out;

  // Workspace (peak ~71.2 MB).
  char* ws = (char*)d_ws;
  unsigned short* hsb  = (unsigned short*)(ws);                       // 16 MiB
  unsigned short* ctxb = (unsigned short*)(ws + ((size_t)16 << 20));  // 16 MiB
  float*          msc  = (float*)(ws + ((size_t)32 << 20));           // 16 MiB
  unsigned short* Wm   = (unsigned short*)(ws + ((size_t)48 << 20));  // 8 MiB
  unsigned short* Wkvt = (unsigned short*)(ws + ((size_t)56 << 20));  // 4 MiB
  unsigned short* Wcat = (unsigned short*)(ws + ((size_t)60 << 20));  // 3 MiB
  unsigned short* Wot  = (unsigned short*)(ws + ((size_t)63 << 20));  // 2 MiB
  unsigned short* mvT  = (unsigned short*)(ws + ((size_t)65 << 20));  // 1 MiB
  unsigned short* kbb  = (unsigned short*)(ws + ((size_t)66 << 20));  // 256 KiB
  unsigned short* vbbT = (unsigned short*)(ws + ((size_t)66 << 20) + ((size_t)256 << 10)); // 256 KiB
  float*          part = (float*)(ws + ((size_t)67 << 20));           // 4 MiB
  float*          imp  = (float*)(ws + ((size_t)71 << 20));           // 32 KiB
  float*          gate = (float*)(ws + ((size_t)71 << 20) + ((size_t)32 << 10));
  int*            lmi  = (int*)  (ws + ((size_t)71 << 20) + ((size_t)96 << 10)); // 4 KiB

  // fused importance/gate/bf16-conversion + weight prep (7168 blocks)
  imp_prep_kernel<<<dim3(2048 + 5120), 256, 0, stream>>>(
      hs, gw, gb, imp, gate, hsb, Wk, Wv, Wq, Wo, mk, mv, Wkvt, Wcat, Wot, mvT);
  // landmark selection by exact rank (single kernel)
  lm_rank_kernel<<<dim3(NS/256, NB), 256, 0, stream>>>(imp, lmi);
  // K/V projection of landmark rows (gather inlined) via MFMA GEMM, split-K=4
  kvproj_gemm_kernel<<<dim3(16, 4), 256, 0, stream>>>(hsb, lmi, Wkvt, part);
  kv_reduce2_kernel<<<dim3(8, 128), 256, 0, stream>>>(part, bk, bv, kbb, vbbT);
  // fused Q-projection + landmark attention + memory scores
  gemm_qattn_kernel<<<dim3(768), 256, 0, stream>>>(hsb, Wcat, bq, kbb, vbbT, ctxb, msc);
  // memory-bank selection -> gate-scaled dense weight rows
  sel_kernel<<<dim3(NTOK/4), 256, 0, stream>>>(msc, gate, Wm);
  // single fused output GEMM: out = ctx@Wot^T + bo + Wm'@mvT^T
  gemm_fused_out_kernel<<<dim3(512), 256, 0, stream>>>(ctxb, Wot, Wm, mvT, bo, out);
}

// Round 18
// 141.069 us; speedup vs baseline: 1.4750x; 1.4750x over previous
//
#include <hip/hip_runtime.h>
#include <math.h>

// Problem constants (from reference setup_inputs)
#define HDIM 1024
#define NHEAD 16
#define HD 64
#define LM 64          // NUM_LANDMARKS
#define MS 512         // memory slots
#define KSEL 32        // top_k
#define NB 2
#define NS 4096
#define NTOK (NB*NS)   // 8192

typedef __attribute__((ext_vector_type(8))) short short8;
typedef __attribute__((ext_vector_type(4))) float f32x4;
typedef __attribute__((ext_vector_type(4))) unsigned short us4;

__device__ __forceinline__ unsigned short f2bf(float f) {
  unsigned int u = __float_as_uint(f);
  unsigned int r = (u + 0x7fffu + ((u >> 16) & 1u)) >> 16;
  return (unsigned short)r;
}
__device__ __forceinline__ float bf2f(unsigned short u) {
  return __uint_as_float(((unsigned int)u) << 16);
}

__device__ __forceinline__ void gload_lds16(const unsigned short* g, unsigned short* l) {
  __builtin_amdgcn_global_load_lds(
      (const __attribute__((address_space(1))) unsigned int*)g,
      (__attribute__((address_space(3))) unsigned int*)l,
      16, 0, 0);
}

// BK=64 tile stager (used by gemm_fused_out): XOR-swizzled source chunks.
#define STAGE64(gbase, k0, LDA, lds)                                          \
  {                                                                           \
    const unsigned short* _s = (gbase) + (k0) + gchk*8;                       \
    gload_lds16(_s,                 (lds) + tid*8);                           \
    gload_lds16(_s + (size_t)32*(LDA), (lds) + 2048 + tid*8);                 \
    gload_lds16(_s + (size_t)64*(LDA), (lds) + 4096 + tid*8);                 \
    gload_lds16(_s + (size_t)96*(LDA), (lds) + 6144 + tid*8);                 \
  }

// ---------------------------------------------------------------------------
// K1 (fused): blocks [0,2048): wave-per-row importance + gate + hs->bf16.
//             blocks [2048,7168): weight transpose/convert prep (flat decode).
// ---------------------------------------------------------------------------
__global__ __launch_bounds__(256) void imp_prep_kernel(
    const float* __restrict__ hs, const float* __restrict__ gw,
    const float* __restrict__ gb, float* __restrict__ imp,
    float* __restrict__ gate, unsigned short* __restrict__ hsb,
    const float* __restrict__ Wk, const float* __restrict__ Wv,
    const float* __restrict__ Wq, const float* __restrict__ Wo,
    const float* __restrict__ mk, const float* __restrict__ mv,
    unsigned short* __restrict__ Wkvt, unsigned short* __restrict__ Wcat,
    unsigned short* __restrict__ Wot, unsigned short* __restrict__ mvT) {
  __shared__ float tile[32][33];
  if (blockIdx.x < 2048) {
    // ---- importance + gate + bf16 conversion ----
    const int lane = threadIdx.x & 63, wave = threadIdx.x >> 6;
    const int row = blockIdx.x*4 + wave;
    float ss = 0.f, dg = 0.f;
#pragma unroll
    for (int c = 0; c < 4; ++c) {
      const int d = c*256 + lane*4;
      const float4 hv = *(const float4*)(hs + (size_t)row*HDIM + d);
      const float4 gv = *(const float4*)(gw + d);
      ss += hv.x*hv.x + hv.y*hv.y + hv.z*hv.z + hv.w*hv.w;
      dg += hv.x*gv.x + hv.y*gv.y + hv.z*gv.z + hv.w*gv.w;
      us4 hb;
      hb.x = f2bf(hv.x); hb.y = f2bf(hv.y); hb.z = f2bf(hv.z); hb.w = f2bf(hv.w);
      *(us4*)(hsb + (size_t)row*HDIM + d) = hb;
    }
#pragma unroll
    for (int off = 32; off > 0; off >>= 1) {
      ss += __shfl_xor(ss, off);
      dg += __shfl_xor(dg, off);
    }
    if (lane == 0) {
      imp[row] = ss;
      gate[row] = 1.f/(1.f + expf(-(dg + gb[0])));
    }
    return;
  }
  // ---- prep ----
  const int flat = blockIdx.x - 2048;       // 0..5119
  const int z = flat >> 10;                 // 0..4
  const int rem = flat & 1023;
  const int byy = rem >> 5, bxx = rem & 31;
  const int tx = threadIdx.x & 31, ty = threadIdx.x >> 5;
  if (z < 4) {
    const float* W = (z == 0) ? Wk : (z == 1) ? Wv : (z == 2) ? Wq : Wo;
    unsigned short* Wt = (z == 0) ? Wkvt
                       : (z == 1) ? (Wkvt + (size_t)HDIM*HDIM)
                       : (z == 2) ? Wcat : Wot;
    const int bx = bxx * 32, by = byy * 32;
#pragma unroll
    for (int i = 0; i < 32; i += 8)
      tile[ty + i][tx] = W[(size_t)(by + ty + i)*HDIM + bx + tx];
    __syncthreads();
#pragma unroll
    for (int i = 0; i < 32; i += 8)
      Wt[(size_t)(bx + ty + i)*HDIM + by + tx] = f2bf(tile[tx][ty + i]);
  } else {
    const int blk = byy*32 + bxx;           // 0..1023
    if (blk < 512) {
      const int off = (blk << 10) + threadIdx.x*4;
      const float4 v = *(const float4*)&mk[off];
      us4 w;
      w.x = f2bf(v.x); w.y = f2bf(v.y); w.z = f2bf(v.z); w.w = f2bf(v.w);
      *(us4*)&(Wcat + (size_t)HDIM*HDIM)[off] = w;
    } else {
      const int t = blk - 512;
      const int by = (t >> 5) * 32;
      const int bx = (t & 31) * 32;
#pragma unroll
      for (int i = 0; i < 32; i += 8)
        tile[ty + i][tx] = mv[(size_t)(by + ty + i)*HDIM + bx + tx];
      __syncthreads();
#pragma unroll
      for (int i = 0; i < 32; i += 8)
        mvT[(size_t)(bx + ty + i)*MS + by + tx] = f2bf(tile[tx][ty + i]);
    }
  }
}

// ---------------------------------------------------------------------------
// K2a: rank counting (jax tie-break). Partial counts per j-chunk written to
// cnt4[jc][b][i] with plain stores (one writer each) — no memset, no atomics.
// 256 blocks x 256-iter loops: enough parallelism to hide latency (R17's
// single-kernel variant at 32 blocks was 100 us latency-bound — reverted).
// ---------------------------------------------------------------------------
__global__ __launch_bounds__(256) void lm_count_kernel(
    const float* __restrict__ imp, int* __restrict__ cnt4) {
  const int b = blockIdx.z;
  const int jc = blockIdx.y;
  const int i = blockIdx.x*256 + threadIdx.x;
  const float* v = imp + b*NS;
  const float mine = v[i];
  __shared__ float tile[1024];
  const int j0 = jc*1024;
  *(float4*)&tile[threadIdx.x*4] = *(const float4*)&v[j0 + threadIdx.x*4];
  __syncthreads();
  int c = 0;
#pragma unroll 8
  for (int p = 0; p < 1024; p += 4) {
    const float4 t = *(const float4*)&tile[p];
    c += (t.x > mine) || (t.x == mine && (j0+p+0) < i);
    c += (t.y > mine) || (t.y == mine && (j0+p+1) < i);
    c += (t.z > mine) || (t.z == mine && (j0+p+2) < i);
    c += (t.w > mine) || (t.w == mine && (j0+p+3) < i);
  }
  cnt4[(size_t)(jc*NB + b)*NS + i] = c;
}

// K2b: sum 4 partials; scatter selected candidates (set only).
__global__ __launch_bounds__(256) void lm_sel_kernel(
    const int* __restrict__ cnt4, int* __restrict__ lm_idx) {
  const int b = blockIdx.y;
  const int i = blockIdx.x*256 + threadIdx.x;
  const int c = cnt4[(size_t)(0*NB + b)*NS + i] + cnt4[(size_t)(1*NB + b)*NS + i]
              + cnt4[(size_t)(2*NB + b)*NS + i] + cnt4[(size_t)(3*NB + b)*NS + i];
  if (c < LM) lm_idx[b*LM + c] = i;
}

// ---------------------------------------------------------------------------
// K3: K/V projection as bf16 MFMA GEMM, split-K=4, landmark gather INLINED.
// ---------------------------------------------------------------------------
__global__ __launch_bounds__(256) void kvproj_gemm_kernel(
    const unsigned short* __restrict__ hsb, const int* __restrict__ lmi,
    const unsigned short* __restrict__ Wkvt, float* __restrict__ part) {
  __shared__ __align__(16) unsigned short As[128*32];
  __shared__ __align__(16) unsigned short Bs[128*32];
  const int tid = threadIdx.x;
  const int lane = tid & 63, wave = tid >> 6;
  const int wr = wave >> 1, wc = wave & 1;
  const int col0 = blockIdx.x << 7;
  const int sp = blockIdx.y;
  const int k00 = sp << 8;

  f32x4 acc[4][4];
#pragma unroll
  for (int m = 0; m < 4; ++m)
#pragma unroll
    for (int n = 0; n < 4; ++n) acc[m][n] = (f32x4)(0.f);

  const int srow = tid >> 2;
  const int sk   = (tid & 3) << 3;
  const int i0 = lmi[srow];            // b=0 landmark row
  const int i1 = lmi[64 + srow];       // b=1 landmark row
  const unsigned short* gA0 = hsb + (size_t)i0*HDIM + sk;
  const unsigned short* gA1 = hsb + ((size_t)NS + i1)*HDIM + sk;
  const unsigned short* gB  = Wkvt + (size_t)(col0 + srow)*HDIM + sk;
  const int fr = lane & 15;
  const int fk = (lane >> 4) << 3;
  const int fg = lane >> 4;

  for (int k0 = k00; k0 < k00 + 256; k0 += 32) {
    gload_lds16(gA0 + k0,            As + tid*8);
    gload_lds16(gA1 + k0,            As + 2048 + tid*8);
    gload_lds16(gB + k0,             Bs + tid*8);
    gload_lds16(gB + 64*HDIM + k0,   Bs + 2048 + tid*8);
    __syncthreads();
    short8 af[4], bf[4];
#pragma unroll
    for (int m = 0; m < 4; ++m)
      af[m] = *(const short8*)&As[(wr*64 + m*16 + fr)*32 + fk];
#pragma unroll
    for (int n = 0; n < 4; ++n)
      bf[n] = *(const short8*)&Bs[(wc*64 + n*16 + fr)*32 + fk];
#pragma unroll
    for (int m = 0; m < 4; ++m)
#pragma unroll
      for (int n = 0; n < 4; ++n)
        acc[m][n] = __builtin_amdgcn_mfma_f32_16x16x32_bf16(af[m], bf[n], acc[m][n], 0, 0, 0);
    __syncthreads();
  }
#pragma unroll
  for (int m = 0; m < 4; ++m)
#pragma unroll
    for (int n = 0; n < 4; ++n) {
      const int colg = col0 + wc*64 + n*16 + fr;
#pragma unroll
      for (int r = 0; r < 4; ++r) {
        const int row = wr*64 + m*16 + fg*4 + r;
        part[((size_t)(sp*128 + row))*2048 + colg] = acc[m][n][r];
      }
    }
}

// K3c: reduce 4 K-split partials + bias -> bf16 K (row-major) and V^T.
__global__ __launch_bounds__(256) void kv_reduce2_kernel(
    const float* __restrict__ part, const float* __restrict__ bk,
    const float* __restrict__ bv, unsigned short* __restrict__ kbb,
    unsigned short* __restrict__ vbbT) {
  const int row = blockIdx.y;                     // 0..127 = b*64 + l
  const int col = blockIdx.x*256 + threadIdx.x;   // 0..2047
  float s = 0.f;
#pragma unroll
  for (int sp = 0; sp < 4; ++sp)
    s += part[((size_t)(sp*128 + row))*2048 + col];
  if (col < HDIM) {
    kbb[(size_t)row*HDIM + col] = f2bf(s + bk[col]);
  } else {
    const int d = col - HDIM;
    const int b = row >> 6, l = row & 63;
    vbbT[(size_t)b*65536 + (size_t)d*64 + l] = f2bf(s + bv[d]);
  }
}

// ---------------------------------------------------------------------------
// K4: FUSED GEMM + ATTENTION.  [q | msc] = hsb @ Wcat^T (BK=32, 128x128).
// bx<8: q-tile (2 heads) in registers; per-wave landmark attention (two
//       32-row passes) via 4KB per-wave LDS buffer. bx>=8: msc epilogue.
// ---------------------------------------------------------------------------
__global__ __launch_bounds__(256, 3) void gemm_qattn_kernel(
    const unsigned short* __restrict__ A,    // hsb
    const unsigned short* __restrict__ Bt,   // Wcat [1536][1024]
    const float* __restrict__ bq,
    const unsigned short* __restrict__ kbb,  // [NB*64][1024]
    const unsigned short* __restrict__ vbbT, // [NB][1024][64]
    unsigned short* __restrict__ ctxb, float* __restrict__ msc) {
  __shared__ __align__(16) unsigned short As[128*32];   // 8 KiB (later wavebuf 0,1)
  __shared__ __align__(16) unsigned short Bs[128*32];   // 8 KiB (later wavebuf 2,3)
  __shared__ __align__(16) unsigned short Ks[2*64*64];  // 16 KiB [h][lm][d]
  __shared__ __align__(16) unsigned short Vt[2*64*64];  // 16 KiB [h][d][lm]
  const int tid = threadIdx.x;
  const int lane = tid & 63, wave = tid >> 6;
  const int wr = wave >> 1, wc = wave & 1;
  const int wg = blockIdx.x;                    // 0..767
  const int swz = (wg & 7)*96 + (wg >> 3);      // bijective XCD swizzle
  const int bx = swz % 12, by = swz / 12;
  const int row0 = by << 7, col0 = bx << 7;
  const int fr = lane & 15;
  const int fk = (lane >> 4) << 3;
  const int fg = lane >> 4;

  // issue K/V staging early (q-blocks only); k-loop barriers drain it
  if (bx < 8) {
    const int b = by >> 5;
#pragma unroll
    for (int it = 0; it < 4; ++it) {
      const int c = it*256 + tid;               // 0..1023
      const int hh = c >> 9, l = (c >> 3) & 63, ch = c & 7;
      gload_lds16(kbb + (size_t)(b*64 + l)*HDIM + (bx*2 + hh)*64 + ch*8,
                  Ks + c*8);
    }
#pragma unroll
    for (int it = 0; it < 4; ++it) {
      const int c = it*256 + tid;
      const int hh = c >> 9, dr = (c >> 3) & 63, ch = c & 7;
      gload_lds16(vbbT + (size_t)(by >> 5)*65536 + (size_t)((bx*2 + hh)*64 + dr)*64 + ch*8,
                  Vt + c*8);
    }
  }

  f32x4 acc[4][4];
#pragma unroll
  for (int m = 0; m < 4; ++m)
#pragma unroll
    for (int n = 0; n < 4; ++n) acc[m][n] = (f32x4)(0.f);

  const int srow = tid >> 2;
  const int sk   = (tid & 3) << 3;
  const unsigned short* gA = A  + (size_t)(row0 + srow)*HDIM + sk;
  const unsigned short* gB = Bt + (size_t)(col0 + srow)*HDIM + sk;

  for (int k0 = 0; k0 < HDIM; k0 += 32) {
    gload_lds16(gA + k0,             As + tid*8);
    gload_lds16(gA + 64*HDIM + k0,   As + 2048 + tid*8);
    gload_lds16(gB + k0,             Bs + tid*8);
    gload_lds16(gB + 64*HDIM + k0,   Bs + 2048 + tid*8);
    __syncthreads();
    short8 af[4], bf[4];
#pragma unroll
    for (int m = 0; m < 4; ++m)
      af[m] = *(const short8*)&As[(wr*64 + m*16 + fr)*32 + fk];
#pragma unroll
    for (int n = 0; n < 4; ++n)
      bf[n] = *(const short8*)&Bs[(wc*64 + n*16 + fr)*32 + fk];
#pragma unroll
    for (int m = 0; m < 4; ++m)
#pragma unroll
      for (int n = 0; n < 4; ++n)
        acc[m][n] = __builtin_amdgcn_mfma_f32_16x16x32_bf16(af[m], bf[n], acc[m][n], 0, 0, 0);
    __syncthreads();
  }

  if (bx >= 8) {
    // msc epilogue
#pragma unroll
    for (int m = 0; m < 4; ++m)
#pragma unroll
      for (int n = 0; n < 4; ++n) {
        const int c2 = col0 + wc*64 + n*16 + fr - HDIM;
#pragma unroll
        for (int r = 0; r < 4; ++r) {
          const int row = row0 + wr*64 + m*16 + fg*4 + r;
          msc[(size_t)row*MS + c2] = acc[m][n][r]*0.03125f;
        }
      }
    return;
  }

  // ---- per-wave landmark attention (64 tokens x 1 head, 2 passes of 32) ----
  float bqv[4];
#pragma unroll
  for (int n = 0; n < 4; ++n) bqv[n] = bq[col0 + wc*64 + n*16 + fr];

  unsigned short* wb = (wave < 2) ? (As + wave*2048) : (Bs + (wave - 2)*2048);
  const int hb = wc*4096;   // head base into Ks/Vt

#pragma unroll
  for (int pass = 0; pass < 2; ++pass) {
    // q (+bias) -> bf16 -> wavebuf [32][64]
#pragma unroll
    for (int m2 = 0; m2 < 2; ++m2)
#pragma unroll
      for (int n = 0; n < 4; ++n)
#pragma unroll
        for (int r = 0; r < 4; ++r)
          wb[(m2*16 + fg*4 + r)*64 + n*16 + fr] =
              f2bf(acc[pass*2 + m2][n][r] + bqv[n]);
    __builtin_amdgcn_wave_barrier();

    // QK^T: scores [32 tok][64 lm]
    f32x4 sc_[2][4];
#pragma unroll
    for (int m2 = 0; m2 < 2; ++m2)
#pragma unroll
      for (int n = 0; n < 4; ++n) sc_[m2][n] = (f32x4)(0.f);
#pragma unroll
    for (int ks = 0; ks < 2; ++ks) {
      short8 af[2], bf[4];
#pragma unroll
      for (int m2 = 0; m2 < 2; ++m2)
        af[m2] = *(const short8*)&wb[(m2*16 + fr)*64 + ks*32 + fk];
#pragma unroll
      for (int n = 0; n < 4; ++n)
        bf[n] = *(const short8*)&Ks[hb + (n*16 + fr)*64 + ks*32 + fk];
#pragma unroll
      for (int m2 = 0; m2 < 2; ++m2)
#pragma unroll
        for (int n = 0; n < 4; ++n)
          sc_[m2][n] = __builtin_amdgcn_mfma_f32_16x16x32_bf16(af[m2], bf[n], sc_[m2][n], 0, 0, 0);
    }

    // in-register row softmax; P -> wavebuf
#pragma unroll
    for (int m2 = 0; m2 < 2; ++m2) {
#pragma unroll
      for (int r = 0; r < 4; ++r) {
        float p0 = sc_[m2][0][r]*0.125f, p1 = sc_[m2][1][r]*0.125f;
        float p2 = sc_[m2][2][r]*0.125f, p3 = sc_[m2][3][r]*0.125f;
        float mx = fmaxf(fmaxf(p0, p1), fmaxf(p2, p3));
#pragma unroll
        for (int off = 1; off < 16; off <<= 1) mx = fmaxf(mx, __shfl_xor(mx, off));
        p0 = expf(p0 - mx); p1 = expf(p1 - mx); p2 = expf(p2 - mx); p3 = expf(p3 - mx);
        float sm = p0 + p1 + p2 + p3;
#pragma unroll
        for (int off = 1; off < 16; off <<= 1) sm += __shfl_xor(sm, off);
        const float inv = 1.f/sm;
        const int prow = (m2*16 + fg*4 + r)*64;
        wb[prow + 0*16 + fr] = f2bf(p0*inv);
        wb[prow + 1*16 + fr] = f2bf(p1*inv);
        wb[prow + 2*16 + fr] = f2bf(p2*inv);
        wb[prow + 3*16 + fr] = f2bf(p3*inv);
      }
    }
    __builtin_amdgcn_wave_barrier();

    // PV: ctx [32 tok][64 dims]
    f32x4 oc_[2][4];
#pragma unroll
    for (int m2 = 0; m2 < 2; ++m2)
#pragma unroll
      for (int n = 0; n < 4; ++n) oc_[m2][n] = (f32x4)(0.f);
#pragma unroll
    for (int ks = 0; ks < 2; ++ks) {
      short8 af[2], bf[4];
#pragma unroll
      for (int m2 = 0; m2 < 2; ++m2)
        af[m2] = *(const short8*)&wb[(m2*16 + fr)*64 + ks*32 + fk];
#pragma unroll
      for (int n = 0; n < 4; ++n)
        bf[n] = *(const short8*)&Vt[hb + (n*16 + fr)*64 + ks*32 + fk];
#pragma unroll
      for (int m2 = 0; m2 < 2; ++m2)
#pragma unroll
        for (int n = 0; n < 4; ++n)
          oc_[m2][n] = __builtin_amdgcn_mfma_f32_16x16x32_bf16(af[m2], bf[n], oc_[m2][n], 0, 0, 0);
    }
#pragma unroll
    for (int m2 = 0; m2 < 2; ++m2)
#pragma unroll
      for (int n = 0; n < 4; ++n)
#pragma unroll
        for (int r = 0; r < 4; ++r) {
          const int tok = row0 + wr*64 + pass*32 + m2*16 + fg*4 + r;
          ctxb[(size_t)tok*HDIM + col0 + wc*64 + n*16 + fr] = f2bf(oc_[m2][n][r]);
        }
    __builtin_amdgcn_wave_barrier();
  }
}

// ---------------------------------------------------------------------------
// K8a: wave-per-token top-32 THRESHOLD selection -> gate-scaled dense weight
// row Wm[token][m] (bf16). Lane-contiguous coalesced I/O.
// ---------------------------------------------------------------------------
__global__ __launch_bounds__(256) void sel_kernel(
    const float* __restrict__ msc, const float* __restrict__ gate,
    unsigned short* __restrict__ Wm) {
  const int tid = threadIdx.x;
  const int lane = tid & 63, wave = tid >> 6;
  const int token = blockIdx.x*4 + wave;

  __shared__ __align__(16) int s_hist[4][256];
  __shared__ unsigned long long s_list[4][256];
  __shared__ int s_B[4], s_above[4], s_nlist[4];

  *(int4*)&s_hist[wave][lane*4] = make_int4(0, 0, 0, 0);
  if (lane == 0) s_nlist[wave] = 0;

  float v[8];
  {
    const float4 va = *(const float4*)&msc[(size_t)token*MS + lane*8];
    const float4 vb = *(const float4*)&msc[(size_t)token*MS + lane*8 + 4];
    v[0] = va.x; v[1] = va.y; v[2] = va.z; v[3] = va.w;
    v[4] = vb.x; v[5] = vb.y; v[6] = vb.z; v[7] = vb.w;
  }

  float mx = v[0], mn = v[0];
#pragma unroll
  for (int j = 1; j < 8; ++j) { mx = fmaxf(mx, v[j]); mn = fminf(mn, v[j]); }
#pragma unroll
  for (int off = 32; off > 0; off >>= 1) {
    mx = fmaxf(mx, __shfl_xor(mx, off));
    mn = fminf(mn, __shfl_xor(mn, off));
  }
  const float range = mx - mn;
  const float scale = (range > 1e-20f) ? 255.f/range : 0.f;

  __builtin_amdgcn_wave_barrier();
  int bins[8];
#pragma unroll
  for (int j = 0; j < 8; ++j) {
    int b = (int)((v[j] - mn)*scale);
    bins[j] = b > 255 ? 255 : b;
    atomicAdd(&s_hist[wave][bins[j]], 1);
  }
  __builtin_amdgcn_wave_barrier();

  const int4 c = *(const int4*)&s_hist[wave][lane*4];
  const int lane_total = c.x + c.y + c.z + c.w;
  int sfx = lane_total;
#pragma unroll
  for (int off = 1; off < 64; off <<= 1) {
    const int src = lane + off;
    int y = __shfl(sfx, src < 64 ? src : lane);
    sfx += (src < 64) ? y : 0;
  }
  const int beyond = sfx - lane_total;
  const int s3 = c.w + beyond;
  const int s2 = c.z + s3;
  const int s1 = c.y + s2;
  const int s0 = c.x + s1;
  int Bl = -1, abv = 0;
  if (s0 >= KSEL && s1 < KSEL) { Bl = lane*4 + 0; abv = s1; }
  if (s1 >= KSEL && s2 < KSEL) { Bl = lane*4 + 1; abv = s2; }
  if (s2 >= KSEL && s3 < KSEL) { Bl = lane*4 + 2; abv = s3; }
  if (s3 >= KSEL && beyond < KSEL) { Bl = lane*4 + 3; abv = beyond; }
  if (Bl >= 0) { s_B[wave] = Bl; s_above[wave] = abv; }
  __builtin_amdgcn_wave_barrier();
  const int B = s_B[wave];
  const int rem = KSEL - s_above[wave];

#pragma unroll
  for (int j = 0; j < 8; ++j) {
    if (bins[j] == B) {
      const unsigned int u = __float_as_uint(v[j]);
      const unsigned int vk = (u & 0x80000000u) ? ~u : (u | 0x80000000u);
      const int p = atomicAdd(&s_nlist[wave], 1);
      if (p < 256)
        s_list[wave][p] = ((unsigned long long)vk << 32) | (unsigned int)~(lane*8 + j);
    }
  }
  __builtin_amdgcn_wave_barrier();

  const int nl = s_nlist[wave] < 256 ? s_nlist[wave] : 256;
  unsigned long long T = ~0ull;
  for (int r = 0; r < rem; ++r) {
    unsigned long long best = 0; int pos = -1;
    for (int i = lane; i < nl; i += 64)
      if (s_list[wave][i] > best) { best = s_list[wave][i]; pos = i; }
#pragma unroll
    for (int off = 32; off > 0; off >>= 1) {
      const unsigned long long ob = __shfl_xor(best, off);
      const int op = __shfl_xor(pos, off);
      if (ob > best) { best = ob; pos = op; }
    }
    if (lane == 0) s_list[wave][pos] = 0;
    T = best;
    __builtin_amdgcn_wave_barrier();
  }

  float e[8];
  float esum = 0.f;
#pragma unroll
  for (int j = 0; j < 8; ++j) {
    bool sel = bins[j] > B;
    if (!sel && bins[j] == B) {
      const unsigned int u = __float_as_uint(v[j]);
      const unsigned int vk = (u & 0x80000000u) ? ~u : (u | 0x80000000u);
      const unsigned long long key =
          ((unsigned long long)vk << 32) | (unsigned int)~(lane*8 + j);
      sel = key >= T;
    }
    e[j] = sel ? expf(v[j] - mx) : 0.f;
    esum += e[j];
  }
#pragma unroll
  for (int off = 32; off > 0; off >>= 1) esum += __shfl_xor(esum, off);
  const float ginv = gate[token]/esum;
  us4 w0, w1;
  w0.x = f2bf(e[0]*ginv); w0.y = f2bf(e[1]*ginv);
  w0.z = f2bf(e[2]*ginv); w0.w = f2bf(e[3]*ginv);
  w1.x = f2bf(e[4]*ginv); w1.y = f2bf(e[5]*ginv);
  w1.z = f2bf(e[6]*ginv); w1.w = f2bf(e[7]*ginv);
  *(us4*)&Wm[(size_t)token*MS + lane*8]     = w0;
  *(us4*)&Wm[(size_t)token*MS + lane*8 + 4] = w1;
}

// ---------------------------------------------------------------------------
// K9: FUSED output GEMM (BK=64, swizzled): out = ctx@Wot^T + bo + Wm'@mvT^T.
// ---------------------------------------------------------------------------
__global__ __launch_bounds__(256) void gemm_fused_out_kernel(
    const unsigned short* __restrict__ A,   // ctxb [NTOK][HDIM]
    const unsigned short* __restrict__ Bt,  // Wot  [HDIM][HDIM]
    const unsigned short* __restrict__ Wm,  // [NTOK][MS] gate-scaled bf16
    const unsigned short* __restrict__ mvT, // [HDIM][MS]
    const float* __restrict__ bias, float* __restrict__ out) {
  __shared__ __align__(16) unsigned short As[128*64];
  __shared__ __align__(16) unsigned short Bs[128*64];
  const int tid = threadIdx.x;
  const int lane = tid & 63, wave = tid >> 6;
  const int wr = wave >> 1, wc = wave & 1;
  const int wg = blockIdx.x;
  const int swz = (wg & 7)*64 + (wg >> 3);
  const int bx = swz & 7, by = swz >> 3;
  const int row0 = by << 7, col0 = bx << 7;

  f32x4 acc[4][4];
#pragma unroll
  for (int m = 0; m < 4; ++m)
#pragma unroll
    for (int n = 0; n < 4; ++n) acc[m][n] = (f32x4)(0.f);

  const int srow = tid >> 3;
  const int gchk = (tid & 7) ^ (srow & 7);
  const int fr = lane & 15;
  const int fg = lane >> 4;
  const int ca = ((0*4 + fg) ^ (fr & 7)) * 8;
  const int cb = ((1*4 + fg) ^ (fr & 7)) * 8;

  {
    const unsigned short* gA = A  + (size_t)(row0 + srow)*HDIM;
    const unsigned short* gB = Bt + (size_t)(col0 + srow)*HDIM;
    for (int k0 = 0; k0 < HDIM; k0 += 64) {
      STAGE64(gA, k0, HDIM, As);
      STAGE64(gB, k0, HDIM, Bs);
      __syncthreads();
#pragma unroll
      for (int kh = 0; kh < 2; ++kh) {
        const int cc = kh ? cb : ca;
        short8 af[4], bf[4];
#pragma unroll
        for (int m = 0; m < 4; ++m)
          af[m] = *(const short8*)&As[(wr*64 + m*16 + fr)*64 + cc];
#pragma unroll
        for (int n = 0; n < 4; ++n)
          bf[n] = *(const short8*)&Bs[(wc*64 + n*16 + fr)*64 + cc];
#pragma unroll
        for (int m = 0; m < 4; ++m)
#pragma unroll
          for (int n = 0; n < 4; ++n)
            acc[m][n] = __builtin_amdgcn_mfma_f32_16x16x32_bf16(af[m], bf[n], acc[m][n], 0, 0, 0);
      }
      __syncthreads();
    }
  }
  {
    const unsigned short* gA = Wm  + (size_t)(row0 + srow)*MS;
    const unsigned short* gB = mvT + (size_t)(col0 + srow)*MS;
    for (int k0 = 0; k0 < MS; k0 += 64) {
      STAGE64(gA, k0, MS, As);
      STAGE64(gB, k0, MS, Bs);
      __syncthreads();
#pragma unroll
      for (int kh = 0; kh < 2; ++kh) {
        const int cc = kh ? cb : ca;
        short8 af[4], bf[4];
#pragma unroll
        for (int m = 0; m < 4; ++m)
          af[m] = *(const short8*)&As[(wr*64 + m*16 + fr)*64 + cc];
#pragma unroll
        for (int n = 0; n < 4; ++n)
          bf[n] = *(const short8*)&Bs[(wc*64 + n*16 + fr)*64 + cc];
#pragma unroll
        for (int m = 0; m < 4; ++m)
#pragma unroll
          for (int n = 0; n < 4; ++n)
            acc[m][n] = __builtin_amdgcn_mfma_f32_16x16x32_bf16(af[m], bf[n], acc[m][n], 0, 0, 0);
      }
      __syncthreads();
    }
  }

#pragma unroll
  for (int m = 0; m < 4; ++m) {
#pragma unroll
    for (int n = 0; n < 4; ++n) {
      const int col = col0 + wc*64 + n*16 + fr;
      const float bb = bias[col];
#pragma unroll
      for (int r = 0; r < 4; ++r) {
        const int row = row0 + wr*64 + m*16 + fg*4 + r;
        out[(size_t)row*HDIM + col] = acc[m][n][r] + bb;
      }
    }
  }
}

// ---------------------------------------------------------------------------
extern "C" void kernel_launch(void* const* d_in, const int* in_sizes, int n_in,
                              void* d_out, int out_size, void* d_ws, size_t ws_size,
                              hipStream_t stream) {
  const float* hs = (const float*)d_in[0];
  const float* Wq = (const float*)d_in[1];
  const float* bq = (const float*)d_in[2];
  const float* Wk = (const float*)d_in[3];
  const float* bk = (const float*)d_in[4];
  const float* Wv = (const float*)d_in[5];
  const float* bv = (const float*)d_in[6];
  const float* Wo = (const float*)d_in[7];
  const float* bo = (const float*)d_in[8];
  const float* mk = (const float*)d_in[9];
  const float* mv = (const float*)d_in[10];
  const float* gw = (const float*)d_in[11];
  const float* gb = (const float*)d_in[12];
  float* out = (float*)d_out;

  // Workspace (peak ~71.2 MB).  cnt4 (128 KB) aliases the part region
  // (dead until kvproj, which runs after lm_sel).
  char* ws = (char*)d_ws;
  unsigned short* hsb  = (unsigned short*)(ws);                       // 16 MiB
  unsigned short* ctxb = (unsigned short*)(ws + ((size_t)16 << 20));  // 16 MiB
  float*          msc  = (float*)(ws + ((size_t)32 << 20));           // 16 MiB
  unsigned short* Wm   = (unsigned short*)(ws + ((size_t)48 << 20));  // 8 MiB
  unsigned short* Wkvt = (unsigned short*)(ws + ((size_t)56 << 20));  // 4 MiB
  unsigned short* Wcat = (unsigned short*)(ws + ((size_t)60 << 20));  // 3 MiB
  unsigned short* Wot  = (unsigned short*)(ws + ((size_t)63 << 20));  // 2 MiB
  unsigned short* mvT  = (unsigned short*)(ws + ((size_t)65 << 20));  // 1 MiB
  unsigned short* kbb  = (unsigned short*)(ws + ((size_t)66 << 20));  // 256 KiB
  unsigned short* vbbT = (unsigned short*)(ws + ((size_t)66 << 20) + ((size_t)256 << 10)); // 256 KiB
  float*          part = (float*)(ws + ((size_t)67 << 20));           // 4 MiB
  int*            cnt4 = (int*)part;                                  // 128 KiB alias
  float*          imp  = (float*)(ws + ((size_t)71 << 20));           // 32 KiB
  float*          gate = (float*)(ws + ((size_t)71 << 20) + ((size_t)32 << 10));
  int*            lmi  = (int*)  (ws + ((size_t)71 << 20) + ((size_t)96 << 10)); // 4 KiB

  // fused importance/gate/bf16-conversion + weight prep (7168 blocks)
  imp_prep_kernel<<<dim3(2048 + 5120), 256, 0, stream>>>(
      hs, gw, gb, imp, gate, hsb, Wk, Wv, Wq, Wo, mk, mv, Wkvt, Wcat, Wot, mvT);
  // landmark selection: parallel rank counting + scatter (R16 structure)
  lm_count_kernel<<<dim3(NS/256, 4, NB), 256, 0, stream>>>(imp, cnt4);
  lm_sel_kernel<<<dim3(NS/256, NB), 256, 0, stream>>>(cnt4, lmi);
  // K/V projection of landmark rows (gather inlined) via MFMA GEMM, split-K=4
  kvproj_gemm_kernel<<<dim3(16, 4), 256, 0, stream>>>(hsb, lmi, Wkvt, part);
  kv_reduce2_kernel<<<dim3(8, 128), 256, 0, stream>>>(part, bk, bv, kbb, vbbT);
  // fused Q-projection + landmark attention + memory scores
  gemm_qattn_kernel<<<dim3(768), 256, 0, stream>>>(hsb, Wcat, bq, kbb, vbbT, ctxb, msc);
  // memory-bank selection -> gate-scaled dense weight rows
  sel_kernel<<<dim3(NTOK/4), 256, 0, stream>>>(msc, gate, Wm);
  // single fused output GEMM: out = ctx@Wot^T + bo + Wm'@mvT^T
  gemm_fused_out_kernel<<<dim3(512), 256, 0, stream>>>(ctxb, Wot, Wm, mvT, bo, out);
}